// Round 5
// baseline (203.013 us; speedup 1.0000x reference)
//
#include <hip/hip_runtime.h>

// FBP fan-beam: weight -> truncated ramp filter (fp16, coef folded)
// -> single backprojection pass: 32x8 pixel tile x ALL 32 batches per block.
// R4 (resubmit; R4 bench was an infra failure): dual-parity bin-pair layout +
// v_dot2_f32_f16 with f32 accumulators (no fp16 drain), 8x contiguous
// swizzled ds_read_b128 gather. Added __has_builtin guard for fdot2.
#define VIEWS 160
#define DETS  640
#define H_IMG 416
#define W_IMG 416
#define BATCH 32

constexpr double D_IMG_D  = 0.006641;
constexpr double D_DET_D  = 0.012858;
constexpr double S2R_D    = 5.95;
constexpr double D2R_D    = 4.906;
constexpr double VIRDET_D = D_DET_D * S2R_D / (S2R_D + D2R_D);
constexpr double PI_D     = 3.14159265358979323846;

typedef __fp16 __attribute__((ext_vector_type(2))) h2f;

#define TILES_X 13
#define TILES_Y 52
#define NTILES  (TILES_X * TILES_Y)   // 676
#define NB      64                    // staged bins per (tile, view)
#define ZSPLIT  2                     // view chunks (80/80)

// pf2 layout: uint element (v, c, e, b) = pack(p16[b][2e+c], p16[b][2e+c+1])
//   v in [0,160), c in {0,1}, e in [0,320), b in [0,32).
//   byte addr = v*81920 + c*40960 + e*128 + b*4.  (13.1 MB total)

__device__ __forceinline__ float dot2_acc(h2f p, h2f w, float acc) {
#if __has_builtin(__builtin_amdgcn_fdot2)
    return __builtin_amdgcn_fdot2(p, w, acc, false);
#else
    return fmaf((float)p.x, (float)w.x, fmaf((float)p.y, (float)w.y, acc));
#endif
}

// ---------------------------------------------------------------------------
// Kernel 0: init = per-view constants + per-(tile,view) stage-window start
// + zero the output. Window math identical to R3 (bs even, NB=64, margin>=5).
// ---------------------------------------------------------------------------
__global__ __launch_bounds__(256) void init_kernel(float* __restrict__ vcs,
                                                   int* __restrict__ bs_tab,
                                                   float4* __restrict__ out4) {
    int t    = threadIdx.x;
    int tile = blockIdx.x;
    if (t < VIEWS) {
        int v = t;
        float dang = (float)(0.009817477 * 4.0);
        float beta = dang * (float)v;
        float cb = cosf(beta), sb = sinf(beta);
        float K  = (float)(S2R_D / VIRDET_D);
        if (tile == 0) {
            ((float4*)vcs)[v] = make_float4(cb, sb, -K * sb, K * cb);
        }
        int ty = tile / TILES_X, tx = tile - ty * TILES_X;
        float XL = ((float)(tx * 32) - 207.5f) * (float)D_IMG_D;
        float XR = ((float)(tx * 32 + 31) - 207.5f) * (float)D_IMG_D;
        float YT = (207.5f - (float)(ty * 8)) * (float)D_IMG_D;
        float YB = (207.5f - (float)(ty * 8 + 7)) * (float)D_IMG_D;
        float m = 1e30f;
#define CORNER(Xc, Yc) { \
        float r_ = -(Xc) * sb + (Yc) * cb; \
        float U_ = (float)S2R_D - (Xc) * cb - (Yc) * sb; \
        float ix = fmaf(K, r_ / U_, 319.5f); \
        m = fminf(m, ix); }
        CORNER(XL, YT); CORNER(XR, YT); CORNER(XL, YB); CORNER(XR, YB);
#undef CORNER
        int bs = (int)floorf(m) - 2;
        bs = max(0, min(DETS - NB, bs)) & ~1;
        bs_tab[tile * VIEWS + v] = bs;
    }
    size_t base = (size_t)tile * 2048 + t;
    float4 z = make_float4(0.f, 0.f, 0.f, 0.f);
    #pragma unroll
    for (int i = 0; i < 8; ++i) out4[base + (size_t)i * 256] = z;
}

// ---------------------------------------------------------------------------
// Kernel 1: weighting + TRUNCATED ramp filter (conv unchanged). Epilogue
// builds the dual-parity bin-pair layout: per (c,e) a uint4 holds this
// block's 4 batches' pairs (p[b][2e+c], p[b][2e+c+1]), assembled from the
// pair-packed columns in s_out via v_perm. Bin 640 is zero-padded.
// ---------------------------------------------------------------------------
#define FT 320
#define RPAD 24            // f4 pad each side (96 floats)
#define RSTR 209           // padded row stride in f4 (24 + 160 + 25)
__global__ __launch_bounds__(FT) void filter_kernel(
    const float* __restrict__ proj, const float* __restrict__ w,
    const float* __restrict__ filt, unsigned int* __restrict__ pf2) {
    __shared__ float4 s_in[4 * RSTR];      // 13376 B zero-padded rows
    __shared__ float  s_f[2 * DETS];       // 5120 B
    __shared__ unsigned int s_out[2 * DETS]; // 5120 B: [sub][bin] = (b_even,b_odd)@bin

    int t = threadIdx.x;
    int g = blockIdx.x;                 // g = group4*160 + v, group4 in [0,8)
    int group4 = g / 160;
    int v = g - group4 * 160;

    for (int e = t; e < 4 * RSTR; e += FT) {
        int ri = e / RSTR, c4 = e - ri * RSTR;
        float4 pv = make_float4(0.f, 0.f, 0.f, 0.f);
        if (c4 >= RPAD && c4 < RPAD + 160) {
            int b = group4 * 4 + ri;
            pv = ((const float4*)(proj + ((size_t)b * VIEWS + v) * DETS))[c4 - RPAD];
            float4 wv = ((const float4*)w)[c4 - RPAD];
            pv.x *= wv.x; pv.y *= wv.y; pv.z *= wv.z; pv.w *= wv.w;
        }
        s_in[e] = pv;
    }
    for (int e = t; e < 2 * DETS; e += FT) s_f[e] = (e < 2 * DETS - 1) ? filt[e] : 0.f;
    __syncthreads();

    int sub = (t >= 160) ? 1 : 0;       // sub 0: rows 0,1; sub 1: rows 2,3
    int tj  = t - sub * 160;

    const float4* f4  = (const float4*)s_f;
    const float4* in4 = &s_in[sub * 2 * RSTR + tj];
    float4 o0 = {0,0,0,0}, o1 = {0,0,0,0};   // even row, odd row
    float4 fp = f4[135];                // wave-uniform window start
    #pragma unroll 2
    for (int u = 0; u < 50; ++u) {
        float4 fn = f4[136 + u];        // wave-uniform
        {
            float4 iv = in4[0 * RSTR + u];
            o0.x = fmaf(iv.x, fp.w, o0.x); o0.x = fmaf(iv.y, fn.x, o0.x);
            o0.x = fmaf(iv.z, fn.y, o0.x); o0.x = fmaf(iv.w, fn.z, o0.x);
            o0.y = fmaf(iv.x, fp.z, o0.y); o0.y = fmaf(iv.y, fp.w, o0.y);
            o0.y = fmaf(iv.z, fn.x, o0.y); o0.y = fmaf(iv.w, fn.y, o0.y);
            o0.z = fmaf(iv.x, fp.y, o0.z); o0.z = fmaf(iv.y, fp.z, o0.z);
            o0.z = fmaf(iv.z, fp.w, o0.z); o0.z = fmaf(iv.w, fn.x, o0.z);
            o0.w = fmaf(iv.x, fp.x, o0.w); o0.w = fmaf(iv.y, fp.y, o0.w);
            o0.w = fmaf(iv.z, fp.z, o0.w); o0.w = fmaf(iv.w, fp.w, o0.w);
        }
        {
            float4 iv = in4[1 * RSTR + u];
            o1.x = fmaf(iv.x, fp.w, o1.x); o1.x = fmaf(iv.y, fn.x, o1.x);
            o1.x = fmaf(iv.z, fn.y, o1.x); o1.x = fmaf(iv.w, fn.z, o1.x);
            o1.y = fmaf(iv.x, fp.z, o1.y); o1.y = fmaf(iv.y, fp.w, o1.y);
            o1.y = fmaf(iv.z, fn.x, o1.y); o1.y = fmaf(iv.w, fn.y, o1.y);
            o1.z = fmaf(iv.x, fp.y, o1.z); o1.z = fmaf(iv.y, fp.z, o1.z);
            o1.z = fmaf(iv.z, fp.w, o1.z); o1.z = fmaf(iv.w, fn.x, o1.z);
            o1.w = fmaf(iv.x, fp.x, o1.w); o1.w = fmaf(iv.y, fp.y, o1.w);
            o1.w = fmaf(iv.z, fp.z, o1.w); o1.w = fmaf(iv.w, fp.w, o1.w);
        }
        fp = fn;
    }

    // fold final scale; pair uint = pkrtz(even, odd) at each bin
    float coef = (float)((PI_D / (double)VIEWS) * S2R_D * S2R_D);
    auto h0 = __builtin_amdgcn_cvt_pkrtz(o0.x * coef, o1.x * coef);
    auto h1 = __builtin_amdgcn_cvt_pkrtz(o0.y * coef, o1.y * coef);
    auto h2 = __builtin_amdgcn_cvt_pkrtz(o0.z * coef, o1.z * coef);
    auto h3 = __builtin_amdgcn_cvt_pkrtz(o0.w * coef, o1.w * coef);
    uint4 pk = make_uint4(__builtin_bit_cast(unsigned int, h0),
                          __builtin_bit_cast(unsigned int, h1),
                          __builtin_bit_cast(unsigned int, h2),
                          __builtin_bit_cast(unsigned int, h3));
    *(uint4*)&s_out[sub * DETS + 4 * tj] = pk;
    __syncthreads();

    // Build dual-parity pairs. Thread t handles (c=0,e=t) and (c=1,e=t).
    // out uint (c,e,b): b = 4*group4 + bi; bi>>1 picks s_out column set,
    // bi&1 picks lo/hi half. perm sel: lo halves 0x05040100, hi 0x07060302.
    unsigned int* dstv = pf2 + (size_t)v * 20480 + (size_t)group4 * 4;
    #pragma unroll
    for (int cc = 0; cc < 2; ++cc) {
        int k  = 2 * t + cc;
        int k1 = k + 1;
        unsigned int u0  = s_out[k];
        unsigned int u0n = (k1 < DETS) ? s_out[k1] : 0u;
        unsigned int u1  = s_out[DETS + k];
        unsigned int u1n = (k1 < DETS) ? s_out[DETS + k1] : 0u;
        uint4 o;
        o.x = __builtin_amdgcn_perm(u0n, u0, 0x05040100u);  // b=4g+0 (lo of sub0)
        o.y = __builtin_amdgcn_perm(u0n, u0, 0x07060302u);  // b=4g+1 (hi of sub0)
        o.z = __builtin_amdgcn_perm(u1n, u1, 0x05040100u);  // b=4g+2 (lo of sub1)
        o.w = __builtin_amdgcn_perm(u1n, u1, 0x07060302u);  // b=4g+3 (hi of sub1)
        *(uint4*)(dstv + (size_t)cc * 10240 + (size_t)t * 32) = o;
    }
}

// ---------------------------------------------------------------------------
// Kernel 2: backprojection over one view-half (80 views). Block = 32x8 pixel
// tile x 32 batches (grid 13x52x2 = 1352, <=6 blocks/CU, one round).
// Per view: stage the tile's window in dual-parity pair layout (8 KB, two
// global_load_lds dwordx4 per thread, XOR-swizzle baked into the GLOBAL
// source address so the linear LDS write lands swizzled), then per pixel:
// geometry once, 8x ds_read_b128 (swizzled) + 32x v_dot2_f32_f16 into f32
// accumulators (no fp16 drain). atomicAdd epilogue.
// LDS chunk j=t (c=j>>8 via +4096, r=(t>>3)&31, k=t&7) holds global chunk
// (c, es+r, k^(r&7)); read addr for logical chunk kg = b2 ^ (kg<<4) with
// b2 = slot + cc*4096 + rr*128 + ((rr&7)<<4).
// ---------------------------------------------------------------------------
__device__ __forceinline__ void gld_lds16(const char* g, char* l) {
    __builtin_amdgcn_global_load_lds(
        (const __attribute__((address_space(1))) unsigned int*)g,
        (__attribute__((address_space(3))) unsigned int*)l, 16, 0, 0);
}

__global__ __launch_bounds__(256, 6) void bp_kernel(
    const unsigned int* __restrict__ pf2, const float* __restrict__ vcs,
    const int* __restrict__ bs_tab, float* __restrict__ out) {
    __shared__ alignas(16) unsigned int s_buf[2 * 2048];  // 2 slots x 8192 B

    int t    = threadIdx.x;
    int half = blockIdx.z;
    int tile = blockIdx.y * TILES_X + blockIdx.x;
    int x    = blockIdx.x * 32 + (t & 31);
    int y    = blockIdx.y * 8 + (t >> 5);

    float X  = ((float)x - 207.5f) * (float)D_IMG_D;
    float Yv = (207.5f - (float)y) * (float)D_IMG_D;

    int vstart = half * (VIEWS / ZSPLIT);
    const float4* vc4 = (const float4*)vcs + vstart;
    const int*    bsp = bs_tab + tile * VIEWS + vstart;
    const char*   pfb = (const char*)pf2 + (size_t)vstart * 81920;

    // thread-const swizzled source offset: r=(t>>3)&31, k=t&7
    int r_s  = (t >> 3) & 31;
    int k_s  = t & 7;
    int toff0 = r_s * 128 + ((k_s ^ (r_s & 7)) << 4);   // c=0 chunk (j=t)
    int wvbase = (t >> 6) << 10;                        // wave-uniform dst base

    float acc[32];
    #pragma unroll
    for (int b = 0; b < 32; ++b) acc[b] = 0.f;

    #define STAGE(c) do { \
        int bsd = bsp[(c)]; \
        const char* src = pfb + (size_t)(c) * 81920 + (size_t)bsd * 64; \
        char* dst = (char*)s_buf + (((c) & 1) << 13) + wvbase; \
        gld_lds16(src + toff0, dst); \
        gld_lds16(src + 40960 + toff0, dst + 4096); \
    } while (0)

    STAGE(0);
    __syncthreads();

    int nv = VIEWS / ZSPLIT;
    for (int c = 0; c < nv; ++c) {
        if (c + 1 < nv) STAGE(c + 1);

        float4 a   = vc4[c];
        int    bsc = bsp[c];
        float U    = fmaf(-X, a.x, fmaf(-Yv, a.y, (float)S2R_D));
        float num  = fmaf(X, a.z, Yv * a.w);
        float ru   = __builtin_amdgcn_rcpf(U);
        float idx  = fmaf(num, ru, 319.5f);
        float idxc = __builtin_amdgcn_fmed3f(idx, 0.f, 639.f);
        float i0f  = fminf(idxc, 638.0f);
        int   i0   = (int)i0f;
        float frac = idxc - truncf(i0f);
        float w2   = ru * ru;
        float wgt  = (idx == idxc) ? w2 : 0.f;
        float w1f  = wgt * frac;
        float w0f  = wgt - w1f;
        h2f w01    = __builtin_amdgcn_cvt_pkrtz(w0f, w1f);  // (w0, w1)

        int rel = min(max(i0 - bsc, 0), NB - 2);  // window-safe (wgt=0 if invalid)
        int cc  = rel & 1;
        int rr  = rel >> 1;
        int b2  = ((c & 1) << 13) + (cc << 12) + (rr << 7) + ((rr & 7) << 4);
        const char* pbase = (const char*)s_buf;
        #pragma unroll
        for (int k = 0; k < 8; ++k) {
            uint4 q = *(const uint4*)(pbase + (b2 ^ (k << 4)));
            acc[4 * k + 0] = dot2_acc(__builtin_bit_cast(h2f, q.x), w01, acc[4 * k + 0]);
            acc[4 * k + 1] = dot2_acc(__builtin_bit_cast(h2f, q.y), w01, acc[4 * k + 1]);
            acc[4 * k + 2] = dot2_acc(__builtin_bit_cast(h2f, q.z), w01, acc[4 * k + 2]);
            acc[4 * k + 3] = dot2_acc(__builtin_bit_cast(h2f, q.w), w01, acc[4 * k + 3]);
        }
        __syncthreads();
    }
    #undef STAGE

    float* ob = out + (size_t)y * W_IMG + x;
    #pragma unroll
    for (int b = 0; b < 32; ++b)
        unsafeAtomicAdd(ob + (size_t)b * (H_IMG * W_IMG), acc[b]);
}

// ---------------------------------------------------------------------------
extern "C" void kernel_launch(void* const* d_in, const int* in_sizes, int n_in,
                              void* d_out, int out_size, void* d_ws, size_t ws_size,
                              hipStream_t stream) {
    const float* proj = (const float*)d_in[0];   // [32,1,160,640]
    const float* w    = (const float*)d_in[1];   // [640]
    const float* filt = (const float*)d_in[2];   // [1279]
    float* out = (float*)d_out;                  // [32,1,416,416]

    float*        vcs    = (float*)d_ws;                         // 2560 B
    int*          bs_tab = (int*)((char*)d_ws + 4096);           // 432,640 B
    unsigned int* pf2    = (unsigned int*)((char*)d_ws + 442368); // 13.1 MB

    init_kernel<<<NTILES, 256, 0, stream>>>(vcs, bs_tab, (float4*)out);
    filter_kernel<<<(BATCH / 4) * VIEWS, FT, 0, stream>>>(proj, w, filt, pf2);
    bp_kernel<<<dim3(TILES_X, TILES_Y, ZSPLIT), 256, 0, stream>>>(pf2, vcs, bs_tab, out);
}

// Round 6
// 191.926 us; speedup vs baseline: 1.0578x; 1.0578x over previous
//
#include <hip/hip_runtime.h>

// FBP fan-beam: weight -> truncated ramp filter (fp16, coef folded)
// -> single backprojection pass: 32x8 pixel tile x ALL 32 batches per block.
// R5: all-parity pair-row layout (128 B/bin: 32 batches x (p[bin],p[bin+1]))
// fixes R4's parity bank-alias (cc*4096 = same banks -> 26M conflicts).
// Slot swizzle s = k ^ (rel&7): Drel 1..7 conflict-free, only Drel=8 aliases.
// v_dot2_f32_f16 + f32 accumulators kept. ZSPLIT=3 at (256,8) restores
// occupancy (2028 blocks, 16 KB LDS, 8 blocks/CU).
#define VIEWS 160
#define DETS  640
#define H_IMG 416
#define W_IMG 416
#define BATCH 32

constexpr double D_IMG_D  = 0.006641;
constexpr double D_DET_D  = 0.012858;
constexpr double S2R_D    = 5.95;
constexpr double D2R_D    = 4.906;
constexpr double VIRDET_D = D_DET_D * S2R_D / (S2R_D + D2R_D);
constexpr double PI_D     = 3.14159265358979323846;

typedef __fp16 __attribute__((ext_vector_type(2))) h2f;

#define TILES_X 13
#define TILES_Y 52
#define NTILES  (TILES_X * TILES_Y)   // 676
#define NB      64                    // staged bins per (tile, view)
#define ZSPLIT  3                     // view chunks (53/53/54)

// pf3 layout: uint element (v, j, b) = pack(p16[b][j], p16[b][j+1])
//   v in [0,160), j in [0,640), b in [0,32).
//   byte addr = v*81920 + j*128 + b*4.  (13.1 MB; bin 640 zero-padded)

__device__ __forceinline__ float dot2_acc(h2f p, h2f w, float acc) {
#if __has_builtin(__builtin_amdgcn_fdot2)
    return __builtin_amdgcn_fdot2(p, w, acc, false);
#else
    return fmaf((float)p.x, (float)w.x, fmaf((float)p.y, (float)w.y, acc));
#endif
}

// ---------------------------------------------------------------------------
// Kernel 0: init = per-view constants + per-(tile,view) stage-window start
// + zero the output. Window math identical to R3/R4 (bs even, NB=64,
// margin>=5).
// ---------------------------------------------------------------------------
__global__ __launch_bounds__(256) void init_kernel(float* __restrict__ vcs,
                                                   int* __restrict__ bs_tab,
                                                   float4* __restrict__ out4) {
    int t    = threadIdx.x;
    int tile = blockIdx.x;
    if (t < VIEWS) {
        int v = t;
        float dang = (float)(0.009817477 * 4.0);
        float beta = dang * (float)v;
        float cb = cosf(beta), sb = sinf(beta);
        float K  = (float)(S2R_D / VIRDET_D);
        if (tile == 0) {
            ((float4*)vcs)[v] = make_float4(cb, sb, -K * sb, K * cb);
        }
        int ty = tile / TILES_X, tx = tile - ty * TILES_X;
        float XL = ((float)(tx * 32) - 207.5f) * (float)D_IMG_D;
        float XR = ((float)(tx * 32 + 31) - 207.5f) * (float)D_IMG_D;
        float YT = (207.5f - (float)(ty * 8)) * (float)D_IMG_D;
        float YB = (207.5f - (float)(ty * 8 + 7)) * (float)D_IMG_D;
        float m = 1e30f;
#define CORNER(Xc, Yc) { \
        float r_ = -(Xc) * sb + (Yc) * cb; \
        float U_ = (float)S2R_D - (Xc) * cb - (Yc) * sb; \
        float ix = fmaf(K, r_ / U_, 319.5f); \
        m = fminf(m, ix); }
        CORNER(XL, YT); CORNER(XR, YT); CORNER(XL, YB); CORNER(XR, YB);
#undef CORNER
        int bs = (int)floorf(m) - 2;
        bs = max(0, min(DETS - NB, bs)) & ~1;
        bs_tab[tile * VIEWS + v] = bs;
    }
    size_t base = (size_t)tile * 2048 + t;
    float4 z = make_float4(0.f, 0.f, 0.f, 0.f);
    #pragma unroll
    for (int i = 0; i < 8; ++i) out4[base + (size_t)i * 256] = z;
}

// ---------------------------------------------------------------------------
// Kernel 1: weighting + TRUNCATED ramp filter (conv unchanged). Epilogue
// builds the all-parity pair-row layout: for each bin j a 128-B row of 32
// batches' pairs (p[b][j], p[b][j+1]); this block contributes its 4 batches
// (16 B at byte offset group4*16). Thread t emits bins 2t and 2t+1 via
// v_perm from the pair-packed columns in s_out. Bin 640 is zero-padded.
// ---------------------------------------------------------------------------
#define FT 320
#define RPAD 24            // f4 pad each side (96 floats)
#define RSTR 209           // padded row stride in f4 (24 + 160 + 25)
__global__ __launch_bounds__(FT) void filter_kernel(
    const float* __restrict__ proj, const float* __restrict__ w,
    const float* __restrict__ filt, unsigned int* __restrict__ pf3) {
    __shared__ float4 s_in[4 * RSTR];      // 13376 B zero-padded rows
    __shared__ float  s_f[2 * DETS];       // 5120 B
    __shared__ unsigned int s_out[2 * DETS]; // 5120 B: [sub][bin] = (b_even,b_odd)@bin

    int t = threadIdx.x;
    int g = blockIdx.x;                 // g = group4*160 + v, group4 in [0,8)
    int group4 = g / 160;
    int v = g - group4 * 160;

    for (int e = t; e < 4 * RSTR; e += FT) {
        int ri = e / RSTR, c4 = e - ri * RSTR;
        float4 pv = make_float4(0.f, 0.f, 0.f, 0.f);
        if (c4 >= RPAD && c4 < RPAD + 160) {
            int b = group4 * 4 + ri;
            pv = ((const float4*)(proj + ((size_t)b * VIEWS + v) * DETS))[c4 - RPAD];
            float4 wv = ((const float4*)w)[c4 - RPAD];
            pv.x *= wv.x; pv.y *= wv.y; pv.z *= wv.z; pv.w *= wv.w;
        }
        s_in[e] = pv;
    }
    for (int e = t; e < 2 * DETS; e += FT) s_f[e] = (e < 2 * DETS - 1) ? filt[e] : 0.f;
    __syncthreads();

    int sub = (t >= 160) ? 1 : 0;       // sub 0: rows 0,1; sub 1: rows 2,3
    int tj  = t - sub * 160;

    const float4* f4  = (const float4*)s_f;
    const float4* in4 = &s_in[sub * 2 * RSTR + tj];
    float4 o0 = {0,0,0,0}, o1 = {0,0,0,0};   // even row, odd row
    float4 fp = f4[135];                // wave-uniform window start
    #pragma unroll 2
    for (int u = 0; u < 50; ++u) {
        float4 fn = f4[136 + u];        // wave-uniform
        {
            float4 iv = in4[0 * RSTR + u];
            o0.x = fmaf(iv.x, fp.w, o0.x); o0.x = fmaf(iv.y, fn.x, o0.x);
            o0.x = fmaf(iv.z, fn.y, o0.x); o0.x = fmaf(iv.w, fn.z, o0.x);
            o0.y = fmaf(iv.x, fp.z, o0.y); o0.y = fmaf(iv.y, fp.w, o0.y);
            o0.y = fmaf(iv.z, fn.x, o0.y); o0.y = fmaf(iv.w, fn.y, o0.y);
            o0.z = fmaf(iv.x, fp.y, o0.z); o0.z = fmaf(iv.y, fp.z, o0.z);
            o0.z = fmaf(iv.z, fp.w, o0.z); o0.z = fmaf(iv.w, fn.x, o0.z);
            o0.w = fmaf(iv.x, fp.x, o0.w); o0.w = fmaf(iv.y, fp.y, o0.w);
            o0.w = fmaf(iv.z, fp.z, o0.w); o0.w = fmaf(iv.w, fp.w, o0.w);
        }
        {
            float4 iv = in4[1 * RSTR + u];
            o1.x = fmaf(iv.x, fp.w, o1.x); o1.x = fmaf(iv.y, fn.x, o1.x);
            o1.x = fmaf(iv.z, fn.y, o1.x); o1.x = fmaf(iv.w, fn.z, o1.x);
            o1.y = fmaf(iv.x, fp.z, o1.y); o1.y = fmaf(iv.y, fp.w, o1.y);
            o1.y = fmaf(iv.z, fn.x, o1.y); o1.y = fmaf(iv.w, fn.y, o1.y);
            o1.z = fmaf(iv.x, fp.y, o1.z); o1.z = fmaf(iv.y, fp.z, o1.z);
            o1.z = fmaf(iv.z, fp.w, o1.z); o1.z = fmaf(iv.w, fn.x, o1.z);
            o1.w = fmaf(iv.x, fp.x, o1.w); o1.w = fmaf(iv.y, fp.y, o1.w);
            o1.w = fmaf(iv.z, fp.z, o1.w); o1.w = fmaf(iv.w, fp.w, o1.w);
        }
        fp = fn;
    }

    // fold final scale; pair uint = pkrtz(even, odd) at each bin
    float coef = (float)((PI_D / (double)VIEWS) * S2R_D * S2R_D);
    auto h0 = __builtin_amdgcn_cvt_pkrtz(o0.x * coef, o1.x * coef);
    auto h1 = __builtin_amdgcn_cvt_pkrtz(o0.y * coef, o1.y * coef);
    auto h2 = __builtin_amdgcn_cvt_pkrtz(o0.z * coef, o1.z * coef);
    auto h3 = __builtin_amdgcn_cvt_pkrtz(o0.w * coef, o1.w * coef);
    uint4 pk = make_uint4(__builtin_bit_cast(unsigned int, h0),
                          __builtin_bit_cast(unsigned int, h1),
                          __builtin_bit_cast(unsigned int, h2),
                          __builtin_bit_cast(unsigned int, h3));
    *(uint4*)&s_out[sub * DETS + 4 * tj] = pk;
    __syncthreads();

    // Emit bin rows j = 2t, 2t+1. uint b for row j = (p[b][j], p[b][j+1]),
    // assembled from column uints via v_perm (lo halves 0x05040100, hi
    // 0x07060302). This block's 4 batches land at byte offset group4*16.
    unsigned int* dstv = pf3 + (size_t)v * 20480 + (size_t)group4 * 4;
    #pragma unroll
    for (int cc = 0; cc < 2; ++cc) {
        int j  = 2 * t + cc;
        int j1 = j + 1;
        unsigned int u0  = s_out[j];
        unsigned int u0n = (j1 < DETS) ? s_out[j1] : 0u;
        unsigned int u1  = s_out[DETS + j];
        unsigned int u1n = (j1 < DETS) ? s_out[DETS + j1] : 0u;
        uint4 o;
        o.x = __builtin_amdgcn_perm(u0n, u0, 0x05040100u);  // b=4g+0
        o.y = __builtin_amdgcn_perm(u0n, u0, 0x07060302u);  // b=4g+1
        o.z = __builtin_amdgcn_perm(u1n, u1, 0x05040100u);  // b=4g+2
        o.w = __builtin_amdgcn_perm(u1n, u1, 0x07060302u);  // b=4g+3
        *(uint4*)(dstv + (size_t)j * 32) = o;
    }
}

// ---------------------------------------------------------------------------
// Kernel 2: backprojection over one view-chunk (53/53/54 views). Block =
// 32x8 pixel tile x 32 batches (grid 13x52x3 = 2028 -> 7.92 blocks/CU at
// (256,8): 16 KB LDS, 32 VGPR). Per view: stage the 64-row window (8 KB,
// two chunk-permuted global_load_lds per thread; permutation baked into the
// GLOBAL source address, LDS write stays linear), then per pixel: geometry
// once, 8x ds_read_b128 at b2 ^ (k<<4) + 32x v_dot2_f32_f16 into f32
// accumulators. atomicAdd epilogue.
// LDS chunk (row r, slot s) holds global chunk k = s ^ (r&7) of window row
// r; read addr for logical chunk k of row rel: b2 ^ (k<<4) with
// b2 = slot + rel*128 + ((rel&7)<<4). Drel 1..7 conflict-free; Drel=8
// aliases (rare, only max-gradient views reach 6 rows/residue).
// ---------------------------------------------------------------------------
__device__ __forceinline__ void gld_lds16(const char* g, char* l) {
    __builtin_amdgcn_global_load_lds(
        (const __attribute__((address_space(1))) unsigned int*)g,
        (__attribute__((address_space(3))) unsigned int*)l, 16, 0, 0);
}

__global__ __launch_bounds__(256, 8) void bp_kernel(
    const unsigned int* __restrict__ pf3, const float* __restrict__ vcs,
    const int* __restrict__ bs_tab, float* __restrict__ out) {
    __shared__ alignas(16) unsigned int s_buf[2 * 2048];  // 2 slots x 8192 B

    int t    = threadIdx.x;
    int zc   = blockIdx.z;
    int tile = blockIdx.y * TILES_X + blockIdx.x;
    int x    = blockIdx.x * 32 + (t & 31);
    int y    = blockIdx.y * 8 + (t >> 5);

    float X  = ((float)x - 207.5f) * (float)D_IMG_D;
    float Yv = (207.5f - (float)y) * (float)D_IMG_D;

    int vstart = (zc * VIEWS) / ZSPLIT;
    int vend   = ((zc + 1) * VIEWS) / ZSPLIT;
    int nv     = vend - vstart;
    const float4* vc4 = (const float4*)vcs + vstart;
    const int*    bsp = bs_tab + tile * VIEWS + vstart;
    const char*   pfb = (const char*)pf3 + (size_t)vstart * 81920;

    // thread-const permuted source offset: r = t>>3 (rows 0..31), k = t&7
    int r_s  = (t >> 3) & 31;
    int k_s  = t & 7;
    int toff0 = r_s * 128 + ((k_s ^ (r_s & 7)) << 4);
    int wvbase = (t >> 6) << 10;                        // wave-uniform dst base

    float acc[32];
    #pragma unroll
    for (int b = 0; b < 32; ++b) acc[b] = 0.f;

    #define STAGE(c) do { \
        int bsd = bsp[(c)]; \
        const char* src = pfb + (size_t)(c) * 81920 + (size_t)bsd * 128 + toff0; \
        char* dst = (char*)s_buf + (((c) & 1) << 13) + wvbase; \
        gld_lds16(src, dst); \
        gld_lds16(src + 4096, dst + 4096); \
    } while (0)

    STAGE(0);
    __syncthreads();

    for (int c = 0; c < nv; ++c) {
        if (c + 1 < nv) STAGE(c + 1);

        float4 a   = vc4[c];
        int    bsc = bsp[c];
        float U    = fmaf(-X, a.x, fmaf(-Yv, a.y, (float)S2R_D));
        float num  = fmaf(X, a.z, Yv * a.w);
        float ru   = __builtin_amdgcn_rcpf(U);
        float idx  = fmaf(num, ru, 319.5f);
        float idxc = __builtin_amdgcn_fmed3f(idx, 0.f, 639.f);
        float i0f  = fminf(idxc, 638.0f);
        int   i0   = (int)i0f;
        float frac = idxc - truncf(i0f);
        float w2   = ru * ru;
        float wgt  = (idx == idxc) ? w2 : 0.f;
        float w1f  = wgt * frac;
        float w0f  = wgt - w1f;
        h2f w01    = __builtin_amdgcn_cvt_pkrtz(w0f, w1f);  // (w0, w1)

        int rel = min(max(i0 - bsc, 0), NB - 2);  // window-safe (wgt=0 if invalid)
        int b2  = ((c & 1) << 13) + (rel << 7) + ((rel & 7) << 4);
        const char* pbase = (const char*)s_buf;
        #pragma unroll
        for (int k = 0; k < 8; ++k) {
            uint4 q = *(const uint4*)(pbase + (b2 ^ (k << 4)));
            acc[4 * k + 0] = dot2_acc(__builtin_bit_cast(h2f, q.x), w01, acc[4 * k + 0]);
            acc[4 * k + 1] = dot2_acc(__builtin_bit_cast(h2f, q.y), w01, acc[4 * k + 1]);
            acc[4 * k + 2] = dot2_acc(__builtin_bit_cast(h2f, q.z), w01, acc[4 * k + 2]);
            acc[4 * k + 3] = dot2_acc(__builtin_bit_cast(h2f, q.w), w01, acc[4 * k + 3]);
        }
        __syncthreads();
    }
    #undef STAGE

    float* ob = out + (size_t)y * W_IMG + x;
    #pragma unroll
    for (int b = 0; b < 32; ++b)
        unsafeAtomicAdd(ob + (size_t)b * (H_IMG * W_IMG), acc[b]);
}

// ---------------------------------------------------------------------------
extern "C" void kernel_launch(void* const* d_in, const int* in_sizes, int n_in,
                              void* d_out, int out_size, void* d_ws, size_t ws_size,
                              hipStream_t stream) {
    const float* proj = (const float*)d_in[0];   // [32,1,160,640]
    const float* w    = (const float*)d_in[1];   // [640]
    const float* filt = (const float*)d_in[2];   // [1279]
    float* out = (float*)d_out;                  // [32,1,416,416]

    float*        vcs    = (float*)d_ws;                         // 2560 B
    int*          bs_tab = (int*)((char*)d_ws + 4096);           // 432,640 B
    unsigned int* pf3    = (unsigned int*)((char*)d_ws + 442368); // 13.1 MB

    init_kernel<<<NTILES, 256, 0, stream>>>(vcs, bs_tab, (float4*)out);
    filter_kernel<<<(BATCH / 4) * VIEWS, FT, 0, stream>>>(proj, w, filt, pf3);
    bp_kernel<<<dim3(TILES_X, TILES_Y, ZSPLIT), 256, 0, stream>>>(pf3, vcs, bs_tab, out);
}

// Round 7
// 188.405 us; speedup vs baseline: 1.0775x; 1.0187x over previous
//
#include <hip/hip_runtime.h>

// FBP fan-beam: weight -> truncated ramp filter (fp16, coef folded)
// -> single backprojection pass: 32x8 pixel tile x ALL 32 batches per block.
// R6: (1) bp geometry software-pipelined one view ahead -- per-view critical
// path is now barrier -> 8 LDS reads (addresses precomputed) -> dot2, with
// next view's geometry chain overlapping the load latency. (2) init fused
// into filter (2 dispatches total). Layout/swizzle identical to R5.
#define VIEWS 160
#define DETS  640
#define H_IMG 416
#define W_IMG 416
#define BATCH 32

constexpr double D_IMG_D  = 0.006641;
constexpr double D_DET_D  = 0.012858;
constexpr double S2R_D    = 5.95;
constexpr double D2R_D    = 4.906;
constexpr double VIRDET_D = D_DET_D * S2R_D / (S2R_D + D2R_D);
constexpr double PI_D     = 3.14159265358979323846;

typedef __fp16 __attribute__((ext_vector_type(2))) h2f;

#define TILES_X 13
#define TILES_Y 52
#define NTILES  (TILES_X * TILES_Y)   // 676
#define NB      64                    // staged bins per (tile, view)
#define ZSPLIT  3                     // view chunks (53/53/54)
#define OUT_F4  ((size_t)BATCH * H_IMG * W_IMG / 4)   // 1,384,448 float4

// pf3 layout: uint element (v, j, b) = pack(p16[b][j], p16[b][j+1])
//   byte addr = v*81920 + j*128 + b*4.  (13.1 MB; bin 640 zero-padded)

__device__ __forceinline__ float dot2_acc(h2f p, h2f w, float acc) {
#if __has_builtin(__builtin_amdgcn_fdot2)
    return __builtin_amdgcn_fdot2(p, w, acc, false);
#else
    return fmaf((float)p.x, (float)w.x, fmaf((float)p.y, (float)w.y, acc));
#endif
}

// ---------------------------------------------------------------------------
// Kernel 1: weighting + TRUNCATED ramp filter (conv unchanged) + fused init
// (vcs, bs_tab, out-zero; replaces init_kernel). Epilogue emits the
// all-parity pair-row layout (128 B/bin: 32 batches x (p[j], p[j+1])).
// ---------------------------------------------------------------------------
#define FT 320
#define RPAD 24            // f4 pad each side (96 floats)
#define RSTR 209           // padded row stride in f4 (24 + 160 + 25)
__global__ __launch_bounds__(FT) void filter_kernel(
    const float* __restrict__ proj, const float* __restrict__ w,
    const float* __restrict__ filt, unsigned int* __restrict__ pf3,
    float* __restrict__ vcs, int* __restrict__ bs_tab,
    float4* __restrict__ out4) {
    __shared__ float4 s_in[4 * RSTR];      // 13376 B zero-padded rows
    __shared__ float  s_f[2 * DETS];       // 5120 B
    __shared__ unsigned int s_out[2 * DETS]; // 5120 B: [sub][bin] = (b_even,b_odd)@bin

    int t = threadIdx.x;
    int g = blockIdx.x;                 // g = group4*160 + v, group4 in [0,8)
    int group4 = g / 160;
    int v = g - group4 * 160;

    // ---- fused init (was init_kernel) ----
    {
        float dang = (float)(0.009817477 * 4.0);
        float K    = (float)(S2R_D / VIRDET_D);
        if (g == 0 && t < VIEWS) {
            float beta = dang * (float)t;
            float cb = cosf(beta), sb = sinf(beta);
            ((float4*)vcs)[t] = make_float4(cb, sb, -K * sb, K * cb);
        }
        int e = g * 85 + t;             // flat (tile*160 + view) index
        if (t < 85 && e < NTILES * VIEWS) {
            int tile = e / 160;
            int vv   = e - tile * 160;
            float beta = dang * (float)vv;
            float cb = cosf(beta), sb = sinf(beta);
            int ty = tile / TILES_X, tx = tile - ty * TILES_X;
            float XL = ((float)(tx * 32) - 207.5f) * (float)D_IMG_D;
            float XR = ((float)(tx * 32 + 31) - 207.5f) * (float)D_IMG_D;
            float YT = (207.5f - (float)(ty * 8)) * (float)D_IMG_D;
            float YB = (207.5f - (float)(ty * 8 + 7)) * (float)D_IMG_D;
            float m = 1e30f;
#define CORNER(Xc, Yc) { \
            float r_ = -(Xc) * sb + (Yc) * cb; \
            float U_ = (float)S2R_D - (Xc) * cb - (Yc) * sb; \
            float ix = fmaf(K, r_ / U_, 319.5f); \
            m = fminf(m, ix); }
            CORNER(XL, YT); CORNER(XR, YT); CORNER(XL, YB); CORNER(XR, YB);
#undef CORNER
            int bs = (int)floorf(m) - 2;
            bs = max(0, min(DETS - NB, bs)) & ~1;
            bs_tab[e] = bs;
        }
        float4 z = make_float4(0.f, 0.f, 0.f, 0.f);
        for (int i = t; i < 1082; i += FT) {
            size_t o = (size_t)g * 1082 + i;
            if (o < OUT_F4) out4[o] = z;
        }
    }

    for (int e = t; e < 4 * RSTR; e += FT) {
        int ri = e / RSTR, c4 = e - ri * RSTR;
        float4 pv = make_float4(0.f, 0.f, 0.f, 0.f);
        if (c4 >= RPAD && c4 < RPAD + 160) {
            int b = group4 * 4 + ri;
            pv = ((const float4*)(proj + ((size_t)b * VIEWS + v) * DETS))[c4 - RPAD];
            float4 wv = ((const float4*)w)[c4 - RPAD];
            pv.x *= wv.x; pv.y *= wv.y; pv.z *= wv.z; pv.w *= wv.w;
        }
        s_in[e] = pv;
    }
    for (int e = t; e < 2 * DETS; e += FT) s_f[e] = (e < 2 * DETS - 1) ? filt[e] : 0.f;
    __syncthreads();

    int sub = (t >= 160) ? 1 : 0;       // sub 0: rows 0,1; sub 1: rows 2,3
    int tj  = t - sub * 160;

    const float4* f4  = (const float4*)s_f;
    const float4* in4 = &s_in[sub * 2 * RSTR + tj];
    float4 o0 = {0,0,0,0}, o1 = {0,0,0,0};   // even row, odd row
    float4 fp = f4[135];                // wave-uniform window start
    #pragma unroll 2
    for (int u = 0; u < 50; ++u) {
        float4 fn = f4[136 + u];        // wave-uniform
        {
            float4 iv = in4[0 * RSTR + u];
            o0.x = fmaf(iv.x, fp.w, o0.x); o0.x = fmaf(iv.y, fn.x, o0.x);
            o0.x = fmaf(iv.z, fn.y, o0.x); o0.x = fmaf(iv.w, fn.z, o0.x);
            o0.y = fmaf(iv.x, fp.z, o0.y); o0.y = fmaf(iv.y, fp.w, o0.y);
            o0.y = fmaf(iv.z, fn.x, o0.y); o0.y = fmaf(iv.w, fn.y, o0.y);
            o0.z = fmaf(iv.x, fp.y, o0.z); o0.z = fmaf(iv.y, fp.z, o0.z);
            o0.z = fmaf(iv.z, fp.w, o0.z); o0.z = fmaf(iv.w, fn.x, o0.z);
            o0.w = fmaf(iv.x, fp.x, o0.w); o0.w = fmaf(iv.y, fp.y, o0.w);
            o0.w = fmaf(iv.z, fp.z, o0.w); o0.w = fmaf(iv.w, fp.w, o0.w);
        }
        {
            float4 iv = in4[1 * RSTR + u];
            o1.x = fmaf(iv.x, fp.w, o1.x); o1.x = fmaf(iv.y, fn.x, o1.x);
            o1.x = fmaf(iv.z, fn.y, o1.x); o1.x = fmaf(iv.w, fn.z, o1.x);
            o1.y = fmaf(iv.x, fp.z, o1.y); o1.y = fmaf(iv.y, fp.w, o1.y);
            o1.y = fmaf(iv.z, fn.x, o1.y); o1.y = fmaf(iv.w, fn.y, o1.y);
            o1.z = fmaf(iv.x, fp.y, o1.z); o1.z = fmaf(iv.y, fp.z, o1.z);
            o1.z = fmaf(iv.z, fp.w, o1.z); o1.z = fmaf(iv.w, fn.x, o1.z);
            o1.w = fmaf(iv.x, fp.x, o1.w); o1.w = fmaf(iv.y, fp.y, o1.w);
            o1.w = fmaf(iv.z, fp.z, o1.w); o1.w = fmaf(iv.w, fp.w, o1.w);
        }
        fp = fn;
    }

    // fold final scale; pair uint = pkrtz(even, odd) at each bin
    float coef = (float)((PI_D / (double)VIEWS) * S2R_D * S2R_D);
    auto h0 = __builtin_amdgcn_cvt_pkrtz(o0.x * coef, o1.x * coef);
    auto h1 = __builtin_amdgcn_cvt_pkrtz(o0.y * coef, o1.y * coef);
    auto h2 = __builtin_amdgcn_cvt_pkrtz(o0.z * coef, o1.z * coef);
    auto h3 = __builtin_amdgcn_cvt_pkrtz(o0.w * coef, o1.w * coef);
    uint4 pk = make_uint4(__builtin_bit_cast(unsigned int, h0),
                          __builtin_bit_cast(unsigned int, h1),
                          __builtin_bit_cast(unsigned int, h2),
                          __builtin_bit_cast(unsigned int, h3));
    *(uint4*)&s_out[sub * DETS + 4 * tj] = pk;
    __syncthreads();

    // Emit bin rows j = 2t, 2t+1 via v_perm (lo 0x05040100, hi 0x07060302);
    // this block's 4 batches land at byte offset group4*16 of each row.
    unsigned int* dstv = pf3 + (size_t)v * 20480 + (size_t)group4 * 4;
    #pragma unroll
    for (int cc = 0; cc < 2; ++cc) {
        int j  = 2 * t + cc;
        int j1 = j + 1;
        unsigned int u0  = s_out[j];
        unsigned int u0n = (j1 < DETS) ? s_out[j1] : 0u;
        unsigned int u1  = s_out[DETS + j];
        unsigned int u1n = (j1 < DETS) ? s_out[DETS + j1] : 0u;
        uint4 o;
        o.x = __builtin_amdgcn_perm(u0n, u0, 0x05040100u);  // b=4g+0
        o.y = __builtin_amdgcn_perm(u0n, u0, 0x07060302u);  // b=4g+1
        o.z = __builtin_amdgcn_perm(u1n, u1, 0x05040100u);  // b=4g+2
        o.w = __builtin_amdgcn_perm(u1n, u1, 0x07060302u);  // b=4g+3
        *(uint4*)(dstv + (size_t)j * 32) = o;
    }
}

// ---------------------------------------------------------------------------
// Kernel 2: backprojection over one view-chunk (53/53/54 views). Block =
// 32x8 pixel tile x 32 batches (grid 13x52x3 = 2028, (256,8): 16 KB LDS).
// Geometry SOFTWARE-PIPELINED one view ahead: at the barrier the current
// view's w01 + read-base are already in registers, so the 8 swizzled
// ds_read_b128 issue immediately; the next view's geometry chain (rcp etc.)
// runs while those loads are in flight. Weight math bit-identical to R5.
// LDS chunk (row r, slot s) holds global chunk k = s ^ (r&7) of window row
// r (permutation baked into the GLOBAL source address); read addr for
// logical chunk k of row rel: b2 ^ (k<<4), b2 = slot + rel*128+((rel&7)<<4).
// ---------------------------------------------------------------------------
__device__ __forceinline__ void gld_lds16(const char* g, char* l) {
    __builtin_amdgcn_global_load_lds(
        (const __attribute__((address_space(1))) unsigned int*)g,
        (__attribute__((address_space(3))) unsigned int*)l, 16, 0, 0);
}

__global__ __launch_bounds__(256, 8) void bp_kernel(
    const unsigned int* __restrict__ pf3, const float* __restrict__ vcs,
    const int* __restrict__ bs_tab, float* __restrict__ out) {
    __shared__ alignas(16) unsigned int s_buf[2 * 2048];  // 2 slots x 8192 B

    int t    = threadIdx.x;
    int zc   = blockIdx.z;
    int tile = blockIdx.y * TILES_X + blockIdx.x;
    int x    = blockIdx.x * 32 + (t & 31);
    int y    = blockIdx.y * 8 + (t >> 5);

    float X  = ((float)x - 207.5f) * (float)D_IMG_D;
    float Yv = (207.5f - (float)y) * (float)D_IMG_D;

    int vstart = (zc * VIEWS) / ZSPLIT;
    int vend   = ((zc + 1) * VIEWS) / ZSPLIT;
    int nv     = vend - vstart;
    const float4* vc4 = (const float4*)vcs + vstart;
    const int*    bsp = bs_tab + tile * VIEWS + vstart;
    const char*   pfb = (const char*)pf3 + (size_t)vstart * 81920;

    // thread-const permuted source offset: r = t>>3 (rows 0..31), k = t&7
    int r_s  = (t >> 3) & 31;
    int k_s  = t & 7;
    int toff0 = r_s * 128 + ((k_s ^ (r_s & 7)) << 4);
    int wvbase = (t >> 6) << 10;                        // wave-uniform dst base

    float acc[32];
    #pragma unroll
    for (int b = 0; b < 32; ++b) acc[b] = 0.f;

    #define STAGE(c) do { \
        int bsd = bsp[(c)]; \
        const char* src = pfb + (size_t)(c) * 81920 + (size_t)bsd * 128 + toff0; \
        char* dst = (char*)s_buf + (((c) & 1) << 13) + wvbase; \
        gld_lds16(src, dst); \
        gld_lds16(src + 4096, dst + 4096); \
    } while (0)

    // geometry (bit-identical to R5), producing packed weights + read base
    #define GEOM(a_, bs_, w01_, b2r_) do { \
        float U    = fmaf(-X, (a_).x, fmaf(-Yv, (a_).y, (float)S2R_D)); \
        float num  = fmaf(X, (a_).z, Yv * (a_).w); \
        float ru   = __builtin_amdgcn_rcpf(U); \
        float idx  = fmaf(num, ru, 319.5f); \
        float idxc = __builtin_amdgcn_fmed3f(idx, 0.f, 639.f); \
        float i0f  = fminf(idxc, 638.0f); \
        int   i0   = (int)i0f; \
        float frac = idxc - truncf(i0f); \
        float w2   = ru * ru; \
        float wgt  = (idx == idxc) ? w2 : 0.f; \
        float w1f  = wgt * frac; \
        float w0f  = wgt - w1f; \
        w01_ = __builtin_amdgcn_cvt_pkrtz(w0f, w1f); \
        int rel = min(max(i0 - (bs_), 0), NB - 2); \
        b2r_ = (rel << 7) + ((rel & 7) << 4); \
    } while (0)

    STAGE(0);
    h2f w01_cur; int b2r_cur;
    {   float4 a0 = vc4[0]; GEOM(a0, bsp[0], w01_cur, b2r_cur); }
    __syncthreads();

    for (int c = 0; c < nv; ++c) {
        if (c + 1 < nv) STAGE(c + 1);

        const char* pbase = (const char*)s_buf + ((c & 1) << 13);
        int b2  = b2r_cur;
        h2f w01 = w01_cur;
        // batch 1: chunks 0..3 issue immediately (addresses precomputed)
        uint4 q0 = *(const uint4*)(pbase + (b2 ^ 0));
        uint4 q1 = *(const uint4*)(pbase + (b2 ^ 16));
        uint4 q2 = *(const uint4*)(pbase + (b2 ^ 32));
        uint4 q3 = *(const uint4*)(pbase + (b2 ^ 48));

        // next view's geometry overlaps the load latency
        if (c + 1 < nv) {
            float4 an = vc4[c + 1];
            GEOM(an, bsp[c + 1], w01_cur, b2r_cur);
        }

        acc[0]  = dot2_acc(__builtin_bit_cast(h2f, q0.x), w01, acc[0]);
        acc[1]  = dot2_acc(__builtin_bit_cast(h2f, q0.y), w01, acc[1]);
        acc[2]  = dot2_acc(__builtin_bit_cast(h2f, q0.z), w01, acc[2]);
        acc[3]  = dot2_acc(__builtin_bit_cast(h2f, q0.w), w01, acc[3]);
        acc[4]  = dot2_acc(__builtin_bit_cast(h2f, q1.x), w01, acc[4]);
        acc[5]  = dot2_acc(__builtin_bit_cast(h2f, q1.y), w01, acc[5]);
        acc[6]  = dot2_acc(__builtin_bit_cast(h2f, q1.z), w01, acc[6]);
        acc[7]  = dot2_acc(__builtin_bit_cast(h2f, q1.w), w01, acc[7]);

        // batch 2: chunks 4..7
        uint4 q4 = *(const uint4*)(pbase + (b2 ^ 64));
        uint4 q5 = *(const uint4*)(pbase + (b2 ^ 80));
        uint4 q6 = *(const uint4*)(pbase + (b2 ^ 96));
        uint4 q7 = *(const uint4*)(pbase + (b2 ^ 112));

        acc[8]  = dot2_acc(__builtin_bit_cast(h2f, q2.x), w01, acc[8]);
        acc[9]  = dot2_acc(__builtin_bit_cast(h2f, q2.y), w01, acc[9]);
        acc[10] = dot2_acc(__builtin_bit_cast(h2f, q2.z), w01, acc[10]);
        acc[11] = dot2_acc(__builtin_bit_cast(h2f, q2.w), w01, acc[11]);
        acc[12] = dot2_acc(__builtin_bit_cast(h2f, q3.x), w01, acc[12]);
        acc[13] = dot2_acc(__builtin_bit_cast(h2f, q3.y), w01, acc[13]);
        acc[14] = dot2_acc(__builtin_bit_cast(h2f, q3.z), w01, acc[14]);
        acc[15] = dot2_acc(__builtin_bit_cast(h2f, q3.w), w01, acc[15]);
        acc[16] = dot2_acc(__builtin_bit_cast(h2f, q4.x), w01, acc[16]);
        acc[17] = dot2_acc(__builtin_bit_cast(h2f, q4.y), w01, acc[17]);
        acc[18] = dot2_acc(__builtin_bit_cast(h2f, q4.z), w01, acc[18]);
        acc[19] = dot2_acc(__builtin_bit_cast(h2f, q4.w), w01, acc[19]);
        acc[20] = dot2_acc(__builtin_bit_cast(h2f, q5.x), w01, acc[20]);
        acc[21] = dot2_acc(__builtin_bit_cast(h2f, q5.y), w01, acc[21]);
        acc[22] = dot2_acc(__builtin_bit_cast(h2f, q5.z), w01, acc[22]);
        acc[23] = dot2_acc(__builtin_bit_cast(h2f, q5.w), w01, acc[23]);
        acc[24] = dot2_acc(__builtin_bit_cast(h2f, q6.x), w01, acc[24]);
        acc[25] = dot2_acc(__builtin_bit_cast(h2f, q6.y), w01, acc[25]);
        acc[26] = dot2_acc(__builtin_bit_cast(h2f, q6.z), w01, acc[26]);
        acc[27] = dot2_acc(__builtin_bit_cast(h2f, q6.w), w01, acc[27]);
        acc[28] = dot2_acc(__builtin_bit_cast(h2f, q7.x), w01, acc[28]);
        acc[29] = dot2_acc(__builtin_bit_cast(h2f, q7.y), w01, acc[29]);
        acc[30] = dot2_acc(__builtin_bit_cast(h2f, q7.z), w01, acc[30]);
        acc[31] = dot2_acc(__builtin_bit_cast(h2f, q7.w), w01, acc[31]);

        __syncthreads();
    }
    #undef STAGE
    #undef GEOM

    float* ob = out + (size_t)y * W_IMG + x;
    #pragma unroll
    for (int b = 0; b < 32; ++b)
        unsafeAtomicAdd(ob + (size_t)b * (H_IMG * W_IMG), acc[b]);
}

// ---------------------------------------------------------------------------
extern "C" void kernel_launch(void* const* d_in, const int* in_sizes, int n_in,
                              void* d_out, int out_size, void* d_ws, size_t ws_size,
                              hipStream_t stream) {
    const float* proj = (const float*)d_in[0];   // [32,1,160,640]
    const float* w    = (const float*)d_in[1];   // [640]
    const float* filt = (const float*)d_in[2];   // [1279]
    float* out = (float*)d_out;                  // [32,1,416,416]

    float*        vcs    = (float*)d_ws;                         // 2560 B
    int*          bs_tab = (int*)((char*)d_ws + 4096);           // 432,640 B
    unsigned int* pf3    = (unsigned int*)((char*)d_ws + 442368); // 13.1 MB

    filter_kernel<<<(BATCH / 4) * VIEWS, FT, 0, stream>>>(proj, w, filt, pf3,
                                                          vcs, bs_tab, (float4*)out);
    bp_kernel<<<dim3(TILES_X, TILES_Y, ZSPLIT), 256, 0, stream>>>(pf3, vcs, bs_tab, out);
}